// Round 4
// baseline (2829.739 us; speedup 1.0000x reference)
//
#include <hip/hip_runtime.h>
#include <cstdint>
#include <cstddef>

// ---------------------------------------------------------------------------
// GAT x3 (exact JAX-threefry dropout, PARTITIONABLE mode) + SAGPool x7.
// Round 4: partitionable random_bits at 32-bit width XORs the two threefry
// output words (jax/_src/prng.py: convert_element_type(bits1 ^ bits2, uint32)).
// Round 3 wrongly used the low word only.
// All segment ops remain deterministic + np-association-matched (CSR serial).
// Workspace: ~95.5 MB.
// ---------------------------------------------------------------------------

__host__ __device__ inline void tf_round(uint32_t &x0, uint32_t &x1, int r) {
  x0 += x1;
  x1 = (x1 << r) | (x1 >> (32 - r));
  x1 ^= x0;
}

// Exact jax threefry2x32 (Random123 KAT: key(0,0),ctr(0,0) -> 6b200159 99ba4efe)
__host__ __device__ inline void threefry2x32(uint32_t k0, uint32_t k1,
                                             uint32_t &x0, uint32_t &x1) {
  uint32_t ks2 = k0 ^ k1 ^ 0x1BD11BDAu;
  x0 += k0; x1 += k1;
  tf_round(x0, x1, 13); tf_round(x0, x1, 15); tf_round(x0, x1, 26); tf_round(x0, x1, 6);
  x0 += k1; x1 += ks2 + 1u;
  tf_round(x0, x1, 17); tf_round(x0, x1, 29); tf_round(x0, x1, 16); tf_round(x0, x1, 24);
  x0 += ks2; x1 += k0 + 2u;
  tf_round(x0, x1, 13); tf_round(x0, x1, 15); tf_round(x0, x1, 26); tf_round(x0, x1, 6);
  x0 += k0; x1 += k1 + 3u;
  tf_round(x0, x1, 17); tf_round(x0, x1, 29); tf_round(x0, x1, 16); tf_round(x0, x1, 24);
  x0 += k1; x1 += ks2 + 4u;
  tf_round(x0, x1, 13); tf_round(x0, x1, 15); tf_round(x0, x1, 26); tf_round(x0, x1, 6);
  x0 += ks2; x1 += k0 + 5u;
}

// ---------------- GEMM: C[M x 200] = A[M x K] @ B[K x 200], fp32 -------------
__global__ __launch_bounds__(256) void gemm200_k(
    const float* __restrict__ A, const float* __restrict__ B,
    float* __restrict__ C, int M, int K) {
  __shared__ __align__(16) float As[128 * 8];
  __shared__ __align__(16) float Bs[8][208];
  int tid = threadIdx.x;
  int m0 = blockIdx.x * 128;
  int r = tid >> 2;
  int colBase = (tid & 3) * 52;
  float acc0[52], acc1[52];
#pragma unroll
  for (int q = 0; q < 52; q++) { acc0[q] = 0.f; acc1[q] = 0.f; }

  for (int k0 = 0; k0 < K; k0 += 8) {
    {
      int row = tid >> 1;
      int c = (tid & 1) * 4;
      int gm = m0 + row;
      float4 v = make_float4(0.f, 0.f, 0.f, 0.f);
      if (gm < M) v = *(const float4*)(A + (size_t)gm * K + (k0 + c));
      *(float4*)(&As[row * 8 + c]) = v;
    }
    for (int t = tid; t < 400; t += 256) {
      int kk = t / 50;
      int c = (t - kk * 50) * 4;
      *(float4*)(&Bs[kk][c]) = *(const float4*)(B + (size_t)(k0 + kk) * 200 + c);
    }
    __syncthreads();
#pragma unroll
    for (int kk = 0; kk < 8; kk++) {
      float a0 = As[r * 8 + kk];
      float a1 = As[(r + 64) * 8 + kk];
#pragma unroll
      for (int q = 0; q < 13; q++) {
        float4 b = *(const float4*)(&Bs[kk][colBase + 4 * q]);
        acc0[4 * q + 0] += a0 * b.x; acc0[4 * q + 1] += a0 * b.y;
        acc0[4 * q + 2] += a0 * b.z; acc0[4 * q + 3] += a0 * b.w;
        acc1[4 * q + 0] += a1 * b.x; acc1[4 * q + 1] += a1 * b.y;
        acc1[4 * q + 2] += a1 * b.z; acc1[4 * q + 3] += a1 * b.w;
      }
    }
    __syncthreads();
  }
  int gm0 = m0 + r, gm1 = m0 + r + 64;
#pragma unroll
  for (int q = 0; q < 52; q++) {
    int col = colBase + q;
    if (col < 200) {
      if (gm0 < M) C[(size_t)gm0 * 200 + col] = acc0[q];
      if (gm1 < M) C[(size_t)gm1 * 200 + col] = acc1[q];
    }
  }
}

// ---------------- dual dot: o1[i]=H[i]·v1, o2[i]=H[i]·v2 (one wave/node) -----
__global__ __launch_bounds__(256) void dual_dot_k(
    const float* __restrict__ H, const float* __restrict__ v1,
    const float* __restrict__ v2, float* __restrict__ o1,
    float* __restrict__ o2, int n) {
  int wave = blockIdx.x * 4 + (threadIdx.x >> 6);
  int lane = threadIdx.x & 63;
  if (wave >= n) return;
  const float* row = H + (size_t)wave * 200;
  float s1 = 0.f, s2 = 0.f;
  for (int d = lane; d < 200; d += 64) {
    float h = row[d];
    s1 += h * v1[d];
    s2 += h * v2[d];
  }
  for (int off = 32; off; off >>= 1) {
    s1 += __shfl_down(s1, off);
    s2 += __shfl_down(s2, off);
  }
  if (lane == 0) { o1[wave] = s1; o2[wave] = s2; }
}

// ---------------- CSR build (dst-sorted, stable by edge index) ---------------
__global__ __launch_bounds__(256) void indeg_k(const int* __restrict__ dst,
                                               int* __restrict__ cnt, int E) {
  int e = blockIdx.x * 256 + threadIdx.x;
  if (e < E) atomicAdd(&cnt[dst[e]], 1);
}

// single block, 256 threads: exclusive scan cnt[0..N) -> rowptr[0..N]
__global__ __launch_bounds__(256) void scan_k(const int* __restrict__ cnt,
                                              int* __restrict__ rowptr, int N) {
  __shared__ int psum[256];
  int t = threadIdx.x;
  int CH = (N + 255) / 256;
  int beg = t * CH, end = min(beg + CH, N);
  if (beg > N) { beg = N; }
  int s = 0;
  for (int i = beg; i < end; i++) s += cnt[i];
  psum[t] = s;
  __syncthreads();
  if (t == 0) {
    int run = 0;
    for (int i = 0; i < 256; i++) { int v = psum[i]; psum[i] = run; run += v; }
  }
  __syncthreads();
  int run = psum[t];
  for (int i = beg; i < end; i++) { rowptr[i] = run; run += cnt[i]; }
  if (end == N && beg <= N) rowptr[N] = run;
}

__global__ __launch_bounds__(256) void cpyint_k(const int* __restrict__ a,
                                                int* __restrict__ b, int n) {
  int i = blockIdx.x * 256 + threadIdx.x;
  if (i < n) b[i] = a[i];
}

__global__ __launch_bounds__(256) void place_k(const int* __restrict__ dst,
                                               int* __restrict__ curs,
                                               int* __restrict__ csr, int E) {
  int e = blockIdx.x * 256 + threadIdx.x;
  if (e >= E) return;
  int pos = atomicAdd(&curs[dst[e]], 1);
  csr[pos] = e;
}

__global__ __launch_bounds__(256) void sortrow_k(const int* __restrict__ rowptr,
                                                 int* __restrict__ csr, int N) {
  int d = blockIdx.x * 256 + threadIdx.x;
  if (d >= N) return;
  int b = rowptr[d], e2 = rowptr[d + 1];
  for (int i = b + 1; i < e2; i++) {
    int v = csr[i];
    int j = i - 1;
    while (j >= b && csr[j] > v) { csr[j + 1] = csr[j]; j--; }
    csr[j + 1] = v;
  }
}

// ---------------- GAT edge softmax (deterministic, np order) -----------------
__device__ inline float dec_ord(unsigned enc) {
  unsigned b = (enc & 0x80000000u) ? (enc ^ 0x80000000u) : ~enc;
  return __uint_as_float(b);
}

__global__ __launch_bounds__(256) void edge_max_k(
    const int* __restrict__ src, const int* __restrict__ dst,
    const float* __restrict__ as_, const float* __restrict__ ad_,
    unsigned* __restrict__ menc, int E, int N) {
  int j = blockIdx.x * 256 + threadIdx.x;
  if (j >= E + N) return;
  int s, d;
  if (j < E) { s = src[j]; d = dst[j]; } else { s = j - E; d = s; }
  float v = as_[s] + ad_[d];
  float ev = (v >= 0.f) ? v : 0.2f * v;  // leaky_relu 0.2
  unsigned b = __float_as_uint(ev);
  unsigned enc = (b & 0x80000000u) ? ~b : (b | 0x80000000u);
  atomicMax(&menc[d], enc);
}

__global__ __launch_bounds__(256) void ee_k(
    const int* __restrict__ src, const int* __restrict__ dst,
    const float* __restrict__ as_, const float* __restrict__ ad_,
    const unsigned* __restrict__ menc, float* __restrict__ ee, int E, int N) {
  int j = blockIdx.x * 256 + threadIdx.x;
  if (j >= E + N) return;
  int s, d;
  if (j < E) { s = src[j]; d = dst[j]; } else { s = j - E; d = s; }
  float v = as_[s] + ad_[d];
  float ev = (v >= 0.f) ? v : 0.2f * v;
  ee[j] = expf(ev - dec_ord(menc[d]));
}

// denom per node: serial sum in edge-index order, self-loop (index E+d) LAST.
__global__ __launch_bounds__(256) void den_k(const int* __restrict__ rowptr,
                                             const int* __restrict__ csr,
                                             const float* __restrict__ ee,
                                             float* __restrict__ den, int E, int N) {
  int d = blockIdx.x * 256 + threadIdx.x;
  if (d >= N) return;
  float s = 0.f;
  int b = rowptr[d], e2 = rowptr[d + 1];
  for (int i = b; i < e2; i++) s = __fadd_rn(s, ee[csr[i]]);
  s = __fadd_rn(s, ee[E + d]);
  den[d] = s;
}

__global__ __launch_bounds__(256) void alpha_k(const int* __restrict__ dst,
                                               const float* __restrict__ den,
                                               float* __restrict__ ee, int E, int N) {
  int j = blockIdx.x * 256 + threadIdx.x;
  if (j >= E + N) return;
  int d = (j < E) ? dst[j] : (j - E);
  ee[j] = ee[j] / den[d];
}

// GAT out: wave per node, serial over edges (edge-index order, self last).
__global__ __launch_bounds__(256) void gat_out_k(
    const int* __restrict__ rowptr, const int* __restrict__ csr,
    const int* __restrict__ src, const float* __restrict__ alpha,
    const float* __restrict__ HW, float* __restrict__ OUT, int E, int N) {
  int node = blockIdx.x * 4 + (threadIdx.x >> 6);
  int lane = threadIdx.x & 63;
  if (node >= N || lane >= 50) return;
  float4 acc = make_float4(0.f, 0.f, 0.f, 0.f);
  int b = rowptr[node], e2 = rowptr[node + 1];
  for (int i = b; i < e2; i++) {
    int e = csr[i];
    int s = src[e];
    float w = alpha[e];
    float4 hv = *(const float4*)(HW + (size_t)s * 200 + 4 * lane);
    acc.x = __fadd_rn(acc.x, __fmul_rn(w, hv.x));
    acc.y = __fadd_rn(acc.y, __fmul_rn(w, hv.y));
    acc.z = __fadd_rn(acc.z, __fmul_rn(w, hv.z));
    acc.w = __fadd_rn(acc.w, __fmul_rn(w, hv.w));
  }
  {
    float w = alpha[E + node];
    float4 hv = *(const float4*)(HW + (size_t)node * 200 + 4 * lane);
    acc.x = __fadd_rn(acc.x, __fmul_rn(w, hv.x));
    acc.y = __fadd_rn(acc.y, __fmul_rn(w, hv.y));
    acc.z = __fadd_rn(acc.z, __fmul_rn(w, hv.z));
    acc.w = __fadd_rn(acc.w, __fmul_rn(w, hv.w));
  }
  *(float4*)(OUT + (size_t)node * 200 + 4 * lane) = acc;
}

// -------- epilogue: bias + relu + JAX partitionable-threefry dropout ---------
// jax_threefry_partitionable=True (default >= 0.4.30), bit_width=32:
//   counts = iota(uint64); bits1,bits2 = threefry2x32(key, hi32(i), lo32(i));
//   bits32 = convert_element_type(bits1 ^ bits2, uint32)   <-- XOR of words
__global__ __launch_bounds__(256) void epi_k(float* __restrict__ H,
                                             const float* __restrict__ bias,
                                             uint32_t k0, uint32_t k1, int total) {
  int t = blockIdx.x * 256 + threadIdx.x;
  if (t >= total) return;
  uint32_t x0 = 0u, x1 = (uint32_t)t;  // hi32(i)=0, lo32(i)=i  (i < 2^32)
  threefry2x32(k0, k1, x0, x1);
  uint32_t bits = x0 ^ x1;
  float u = __uint_as_float((bits >> 9) | 0x3f800000u) - 1.0f;
  int col = t % 200;
  float v = H[t] + bias[col];
  v = fmaxf(v, 0.f);
  H[t] = (u < 0.8f) ? (v / 0.8f) : 0.f;
}

// ---------------- pooling kernels -------------------------------------------
__global__ __launch_bounds__(256) void einit_k(
    const int* __restrict__ src, const int* __restrict__ dst,
    int* __restrict__ cs, int* __restrict__ cd, int* __restrict__ orig,
    int E, int N) {
  int e = blockIdx.x * 256 + threadIdx.x;
  if (e < E) { cs[e] = src[e]; cd[e] = dst[e]; }
  if (e < N) orig[e] = e;
}

// agg[d'] = sum over valid edges (orig CSR row of orig[d'], ascending e) of h[csrc[e]]
__global__ __launch_bounds__(256) void pool_agg_k(
    const int* __restrict__ rowptr, const int* __restrict__ csr,
    const int* __restrict__ csrc, const int* __restrict__ orig,
    const float* __restrict__ H, float* __restrict__ AGG, int n) {
  int node = blockIdx.x * 4 + (threadIdx.x >> 6);
  int lane = threadIdx.x & 63;
  if (node >= n || lane >= 50) return;
  int o = orig[node];
  float4 acc = make_float4(0.f, 0.f, 0.f, 0.f);
  int b = rowptr[o], e2 = rowptr[o + 1];
  for (int i = b; i < e2; i++) {
    int e = csr[i];
    int s = csrc[e];
    if (s < 0) continue;
    float4 hv = *(const float4*)(H + (size_t)s * 200 + 4 * lane);
    acc.x = __fadd_rn(acc.x, hv.x);
    acc.y = __fadd_rn(acc.y, hv.y);
    acc.z = __fadd_rn(acc.z, hv.z);
    acc.w = __fadd_rn(acc.w, hv.w);
  }
  *(float4*)(AGG + (size_t)node * 200 + 4 * lane) = acc;
}

// score[i] = tanh((agg_i . Wrel + h_i . Wroot) + b)
__global__ __launch_bounds__(256) void score2_k(
    const float* __restrict__ AGG, const float* __restrict__ H,
    const float* __restrict__ wrel, const float* __restrict__ wroot,
    const float* __restrict__ bp, float* __restrict__ score, int n) {
  int node = blockIdx.x * 4 + (threadIdx.x >> 6);
  int lane = threadIdx.x & 63;
  if (node >= n) return;
  const float* arow = AGG + (size_t)node * 200;
  const float* hrow = H + (size_t)node * 200;
  float s1 = 0.f, s2 = 0.f;
  for (int d = lane; d < 200; d += 64) {
    s1 += arow[d] * wrel[d];
    s2 += hrow[d] * wroot[d];
  }
  for (int off = 32; off; off >>= 1) {
    s1 += __shfl_down(s1, off);
    s2 += __shfl_down(s2, off);
  }
  if (lane == 0) score[node] = tanhf((s1 + s2) + bp[0]);
}

// rank[i] = #{j : score[j] > score[i] or (== and j < i)}  (lax.top_k order)
__global__ __launch_bounds__(256) void rank_k(const float* __restrict__ score,
                                              int* __restrict__ rank, int n) {
  __shared__ float sc[256];
  int i = blockIdx.x * 256 + threadIdx.x;
  int nseg = gridDim.y, seg = blockIdx.y;
  int jbeg = (int)(((long long)n * seg) / nseg);
  int jend = (int)(((long long)n * (seg + 1)) / nseg);
  float si = (i < n) ? score[i] : 0.f;
  int cnt = 0;
  for (int base = jbeg; base < jend; base += 256) {
    int j = base + threadIdx.x;
    sc[threadIdx.x] = (j < jend) ? score[j] : 0.f;
    __syncthreads();
    int lim = min(256, jend - base);
#pragma unroll 8
    for (int t = 0; t < lim; t++) {
      float sj = sc[t];
      cnt += ((sj > si) || (sj == si && (base + t) < i)) ? 1 : 0;
    }
    __syncthreads();
  }
  if (i < n) atomicAdd(&rank[i], cnt);
}

__global__ __launch_bounds__(256) void perm_inv_k(const int* __restrict__ rank,
                                                  int* __restrict__ perm,
                                                  int* __restrict__ inv,
                                                  int n, int k) {
  int i = blockIdx.x * 256 + threadIdx.x;
  if (i >= n) return;
  int r = rank[i];
  if (r < k) { perm[r] = i; inv[i] = r; }
  else inv[i] = -1;
}

__global__ __launch_bounds__(256) void orig_update_k(const int* __restrict__ perm,
                                                     const int* __restrict__ oin,
                                                     int* __restrict__ oout, int k) {
  int r = blockIdx.x * 256 + threadIdx.x;
  if (r < k) oout[r] = oin[perm[r]];
}

__global__ __launch_bounds__(256) void gather_k(
    const float* __restrict__ H, const int* __restrict__ perm,
    const float* __restrict__ score, float* __restrict__ Ho, int k) {
  int r = blockIdx.x;
  int d = threadIdx.x;
  int p = perm[r];
  float s = score[p];
  if (d < 200) Ho[(size_t)r * 200 + d] = __fmul_rn(H[(size_t)p * 200 + d], s);
}

__global__ __launch_bounds__(256) void remap_k(int* __restrict__ cs,
                                               int* __restrict__ cd,
                                               const int* __restrict__ inv, int E) {
  int e = blockIdx.x * 256 + threadIdx.x;
  if (e >= E) return;
  int a = cs[e];
  if (a < 0) return;  // already invalid, stays invalid
  int na = inv[a], nb = inv[cd[e]];
  bool valid = (na >= 0) && (nb >= 0);
  cs[e] = valid ? na : -1;
  cd[e] = valid ? nb : -1;
}

__global__ __launch_bounds__(256) void out_copy_k(const float* __restrict__ h,
                                                  float* __restrict__ out, int cnt) {
  int t = blockIdx.x * 256 + threadIdx.x;
  if (t < cnt) out[t] = h[t];
}

// ---------------------------------------------------------------------------
extern "C" void kernel_launch(void* const* d_in, const int* in_sizes, int n_in,
                              void* d_out, int out_size, void* d_ws, size_t ws_size,
                              hipStream_t stream) {
  const int ID = 128, HD = 200;
  const int N = in_sizes[0] / ID;   // 50000
  const int E = in_sizes[1];        // 800000
  const int ET = E + N;
  const int total = N * HD;         // 10,000,000

  const float* x = (const float*)d_in[0];
  const int* src = (const int*)d_in[1];
  const int* dst = (const int*)d_in[2];
  const float* W[3]   = {(const float*)d_in[3], (const float*)d_in[7], (const float*)d_in[11]};
  const float* asv[3] = {(const float*)d_in[4], (const float*)d_in[8], (const float*)d_in[12]};
  const float* adv[3] = {(const float*)d_in[5], (const float*)d_in[9], (const float*)d_in[13]};
  const float* bv[3]  = {(const float*)d_in[6], (const float*)d_in[10], (const float*)d_in[14]};
  const float* Wrel  = (const float*)d_in[15];
  const float* Wroot = (const float*)d_in[16];
  const float* bpool = (const float*)d_in[17];

  char* ws = (char*)d_ws;
  float*    bufA  = (float*)(ws + 0);           // 40,000,000
  float*    bufB  = (float*)(ws + 40000000);    // 40,000,000
  float*    as_   = (float*)(ws + 80000000);    //   200,000
  float*    ad_   = (float*)(ws + 80200000);    //   200,000
  float*    ee_   = (float*)(ws + 80400000);    // 3,400,000
  unsigned* menc  = (unsigned*)(ws + 83800000); //   200,000
  float*    den   = (float*)(ws + 84000000);    //   200,000
  float*    score = (float*)(ws + 84200000);    //   200,000
  int*      rank_ = (int*)(ws + 84400000);      //   200,000 (also CSR count)
  int*      perm_ = (int*)(ws + 84600000);      //   200,000
  int*      inv_  = (int*)(ws + 84800000);      //   200,000
  int*      origA = (int*)(ws + 85000000);      //   200,000
  int*      origB = (int*)(ws + 85200000);      //   200,000
  int*      rowptr= (int*)(ws + 85400000);      //   250,000 (N+1 ints)
  int*      curs  = (int*)(ws + 85650000);      //   200,000
  int*      csr   = (int*)(ws + 85850000);      // 3,200,000
  int*      csrc  = (int*)(ws + 89050000);      // 3,200,000
  int*      cdst  = (int*)(ws + 92250000);      // 3,200,000  -> total 95.45 MB

  // Host-side fold_in(key(42), i) = threefry2x32(k=(0,42), x=(0,i)).
  // (fold_in uses raw threefry_2x32 on the seed-expanded count — flag-independent.)
  uint32_t fk0[3], fk1[3];
  for (int i = 0; i < 3; i++) {
    uint32_t a = 0u, b = (uint32_t)i;
    threefry2x32(0u, 42u, a, b);
    fk0[i] = a; fk1[i] = b;
  }

  const int B256 = 256;
  // ---------------- CSR build (once) ----------------
  hipMemsetAsync(rank_, 0, (size_t)N * 4, stream);
  indeg_k<<<(E + 255) / 256, B256, 0, stream>>>(dst, rank_, E);
  scan_k<<<1, B256, 0, stream>>>(rank_, rowptr, N);
  cpyint_k<<<(N + 255) / 256, B256, 0, stream>>>(rowptr, curs, N);
  place_k<<<(E + 255) / 256, B256, 0, stream>>>(dst, curs, csr, E);
  sortrow_k<<<(N + 255) / 256, B256, 0, stream>>>(rowptr, csr, N);

  // ---------------- 3 GAT layers ----------------
  for (int i = 0; i < 3; i++) {
    const float* in = (i == 0) ? x : bufB;
    int K = (i == 0) ? ID : HD;
    gemm200_k<<<(N + 127) / 128, B256, 0, stream>>>(in, W[i], bufA, N, K);
    dual_dot_k<<<(N + 3) / 4, B256, 0, stream>>>(bufA, asv[i], adv[i], as_, ad_, N);
    hipMemsetAsync(menc, 0, (size_t)N * 4, stream);
    edge_max_k<<<(ET + 255) / 256, B256, 0, stream>>>(src, dst, as_, ad_, menc, E, N);
    ee_k<<<(ET + 255) / 256, B256, 0, stream>>>(src, dst, as_, ad_, menc, ee_, E, N);
    den_k<<<(N + 255) / 256, B256, 0, stream>>>(rowptr, csr, ee_, den, E, N);
    alpha_k<<<(ET + 255) / 256, B256, 0, stream>>>(dst, den, ee_, E, N);
    gat_out_k<<<(N + 3) / 4, B256, 0, stream>>>(rowptr, csr, src, ee_, bufA, bufB, E, N);
    epi_k<<<(total + 255) / 256, B256, 0, stream>>>(bufB, bv[i], fk0[i], fk1[i], total);
  }

  // ---------------- SAGPooling loop ----------------
  einit_k<<<(E + 255) / 256, B256, 0, stream>>>(src, dst, csrc, cdst, origA, E, N);
  float* hcur = bufB;
  float* hnext = bufA;   // also serves as AGG scratch each round
  int* ocur = origA;
  int* onext = origB;
  int n = N;
  while (true) {
    int k = (n + 1) / 2;  // ceil(0.5 n)
    pool_agg_k<<<(n + 3) / 4, B256, 0, stream>>>(rowptr, csr, csrc, ocur, hcur, hnext, n);
    score2_k<<<(n + 3) / 4, B256, 0, stream>>>(hnext, hcur, Wrel, Wroot, bpool, score, n);
    hipMemsetAsync(rank_, 0, (size_t)n * 4, stream);
    {
      dim3 grid((n + 255) / 256, 8);
      rank_k<<<grid, B256, 0, stream>>>(score, rank_, n);
    }
    perm_inv_k<<<(n + 255) / 256, B256, 0, stream>>>(rank_, perm_, inv_, n, k);
    orig_update_k<<<(k + 255) / 256, B256, 0, stream>>>(perm_, ocur, onext, k);
    gather_k<<<k, B256, 0, stream>>>(hcur, perm_, score, hnext, k);
    remap_k<<<(E + 255) / 256, B256, 0, stream>>>(csrc, cdst, inv_, E);
    { float* t = hcur; hcur = hnext; hnext = t; }
    { int* t = ocur; ocur = onext; onext = t; }
    n = k;
    if (n <= 512) break;
  }

  // ---------------- output: zeros(512,200) with first n rows = h -------------
  hipMemsetAsync(d_out, 0, (size_t)out_size * 4, stream);
  out_copy_k<<<(n * HD + 255) / 256, B256, 0, stream>>>(hcur, (float*)d_out, n * HD);
}